// Round 1
// baseline (599.661 us; speedup 1.0000x reference)
//
#include <hip/hip_runtime.h>

#define KNBR 32
#define DIN  70
#define DHID 128
#define DOUT 64

__device__ __forceinline__ float gelu_tanh(float v) {
    const float c0 = 0.7978845608028654f;   // sqrt(2/pi)
    const float c1 = 0.044715f;
    float u = c0 * (v + c1 * v * v * v);
    return 0.5f * v * (1.0f + tanhf(u));
}

__global__ __launch_bounds__(256) void it_fused_kernel(
    const float* __restrict__ y,     // [n_in][3]
    const float* __restrict__ xq,    // [n_out][3]
    const float* __restrict__ f_y,   // [n_in][64]
    const float* __restrict__ W1,    // [70][128]
    const float* __restrict__ b1,    // [128]
    const float* __restrict__ W2,    // [128][64]
    const float* __restrict__ b2,    // [64]
    const float* __restrict__ av,    // [128]
    const int*   __restrict__ nbr,   // [n_out*32]
    float*       __restrict__ out,   // [n_out][64]
    int n_out)
{
    __shared__ float s_inT[DIN][KNBR];        // edge_in transposed
    __shared__ float s_hT[DHID][KNBR + 1];    // h transposed, +1 pad
    __shared__ float s_score[KNBR];
    __shared__ float s_alpha[KNBR];

    const int q   = blockIdx.x;
    const int tid = threadIdx.x;

    // ---------------- phase 1: gather edge_in^T ----------------
    {
        const int e    = tid & 31;   // edge
        const int part = tid >> 5;   // 0..7, 8 threads per edge
        const int ni   = nbr[q * KNBR + e];
        if (part == 0) {
            s_inT[0][e] = y[ni * 3 + 0];
            s_inT[1][e] = y[ni * 3 + 1];
            s_inT[2][e] = y[ni * 3 + 2];
            s_inT[3][e] = xq[q * 3 + 0];
            s_inT[4][e] = xq[q * 3 + 1];
            s_inT[5][e] = xq[q * 3 + 2];
        }
        const float4* fv = (const float4*)(f_y + (long)ni * 64);
        float4 v0 = fv[part * 2 + 0];
        float4 v1 = fv[part * 2 + 1];
        const int r = 6 + part * 8;
        s_inT[r + 0][e] = v0.x; s_inT[r + 1][e] = v0.y;
        s_inT[r + 2][e] = v0.z; s_inT[r + 3][e] = v0.w;
        s_inT[r + 4][e] = v1.x; s_inT[r + 5][e] = v1.y;
        s_inT[r + 6][e] = v1.z; s_inT[r + 7][e] = v1.w;
    }
    __syncthreads();

    // ---------------- phase 2: GEMM1  h = edge_in @ W1 ----------------
    // thread tile: 4 edges (eg) x 4 hidden (jg)
    const int jg = tid & 31;    // hidden group: j = 4*jg .. 4*jg+3
    const int eg = tid >> 5;    // edge group 0..7: e = 4*eg .. 4*eg+3
    float acc[4][4];
    #pragma unroll
    for (int i = 0; i < 4; ++i)
        #pragma unroll
        for (int j = 0; j < 4; ++j) acc[i][j] = 0.0f;

    const float4* W1v = (const float4*)W1;
    #pragma unroll 2
    for (int k = 0; k < DIN; ++k) {
        float4 a4 = *(const float4*)&s_inT[k][4 * eg];
        float4 b4 = W1v[k * 32 + jg];
        float aa[4] = {a4.x, a4.y, a4.z, a4.w};
        float bb[4] = {b4.x, b4.y, b4.z, b4.w};
        #pragma unroll
        for (int i = 0; i < 4; ++i)
            #pragma unroll
            for (int j = 0; j < 4; ++j)
                acc[i][j] = fmaf(aa[i], bb[j], acc[i][j]);
    }

    // ---------------- phase 3: bias + gelu + store h^T + scores ----------------
    {
        float4 b14 = ((const float4*)b1)[jg];
        float4 a14 = ((const float4*)av)[jg];
        float bb[4] = {b14.x, b14.y, b14.z, b14.w};
        float aa[4] = {a14.x, a14.y, a14.z, a14.w};
        float sc[4] = {0.f, 0.f, 0.f, 0.f};
        #pragma unroll
        for (int j = 0; j < 4; ++j) {
            #pragma unroll
            for (int i = 0; i < 4; ++i) {
                float h = gelu_tanh(acc[i][j] + bb[j]);
                s_hT[4 * jg + j][4 * eg + i] = h;
                sc[i] = fmaf(h, aa[j], sc[i]);
            }
        }
        // reduce over jg (lane bits 0..4 within each 32-lane half)
        #pragma unroll
        for (int m = 1; m < 32; m <<= 1) {
            #pragma unroll
            for (int i = 0; i < 4; ++i) sc[i] += __shfl_xor(sc[i], m, 64);
        }
        if (jg == 0) {
            #pragma unroll
            for (int i = 0; i < 4; ++i) s_score[4 * eg + i] = sc[i];
        }
    }
    __syncthreads();

    // ---------------- phase 4: softmax over K=32 ----------------
    if (tid < 32) {
        float s  = s_score[tid];
        float mx = s;
        #pragma unroll
        for (int m = 1; m < 32; m <<= 1) mx = fmaxf(mx, __shfl_xor(mx, m, 64));
        float ex  = __expf(s - mx);
        float sum = ex;
        #pragma unroll
        for (int m = 1; m < 32; m <<= 1) sum += __shfl_xor(sum, m, 64);
        s_alpha[tid] = ex / sum;
    }
    __syncthreads();

    // ---------------- phase 5: GEMM2 + weighted reduce ----------------
    // thread tile: 2 edges (eg2) x 4 outs (og)
    const int eg2 = tid & 15;   // edges 2*eg2, 2*eg2+1
    const int og  = tid >> 4;   // outs 4*og .. 4*og+3
    float acc0[4] = {0.f, 0.f, 0.f, 0.f};
    float acc1[4] = {0.f, 0.f, 0.f, 0.f};
    const float4* W2v = (const float4*)W2;
    #pragma unroll 4
    for (int k = 0; k < DHID; ++k) {
        float h0 = s_hT[k][2 * eg2 + 0];
        float h1 = s_hT[k][2 * eg2 + 1];
        float4 w4 = W2v[k * 16 + og];
        float ww[4] = {w4.x, w4.y, w4.z, w4.w};
        #pragma unroll
        for (int j = 0; j < 4; ++j) {
            acc0[j] = fmaf(h0, ww[j], acc0[j]);
            acc1[j] = fmaf(h1, ww[j], acc1[j]);
        }
    }
    const float al0 = s_alpha[2 * eg2 + 0];
    const float al1 = s_alpha[2 * eg2 + 1];
    float o[4];
    #pragma unroll
    for (int j = 0; j < 4; ++j) {
        o[j] = al0 * acc0[j] + al1 * acc1[j];
        #pragma unroll
        for (int m = 1; m < 16; m <<= 1) o[j] += __shfl_xor(o[j], m, 64);
    }
    if (eg2 == 0) {
        float4 b24 = ((const float4*)b2)[og];
        float4 res;
        res.x = o[0] + b24.x;
        res.y = o[1] + b24.y;
        res.z = o[2] + b24.z;
        res.w = o[3] + b24.w;
        ((float4*)out)[q * 16 + og] = res;
    }
}

extern "C" void kernel_launch(void* const* d_in, const int* in_sizes, int n_in,
                              void* d_out, int out_size, void* d_ws, size_t ws_size,
                              hipStream_t stream) {
    const float* y   = (const float*)d_in[0];
    const float* xq  = (const float*)d_in[1];
    const float* f_y = (const float*)d_in[2];
    const float* W1  = (const float*)d_in[3];
    const float* b1  = (const float*)d_in[4];
    const float* W2  = (const float*)d_in[5];
    const float* b2  = (const float*)d_in[6];
    const float* av  = (const float*)d_in[7];
    const int*   nbr = (const int*)d_in[8];
    float* out = (float*)d_out;

    const int n_out = in_sizes[1] / 3;   // x is [n_out][3]
    it_fused_kernel<<<n_out, 256, 0, stream>>>(y, xq, f_y, W1, b1, W2, b2, av, nbr, out, n_out);
}

// Round 2
// 145.719 us; speedup vs baseline: 4.1152x; 4.1152x over previous
//
#include <hip/hip_runtime.h>

typedef __attribute__((ext_vector_type(8))) short bf16x8;
typedef __attribute__((ext_vector_type(4))) float f32x4;

#define KNBR 32

__device__ __forceinline__ unsigned short f2bf(float f) {
    unsigned u = __float_as_uint(f);
    u += 0x7FFFu + ((u >> 16) & 1u);          // RNE to bf16
    return (unsigned short)(u >> 16);
}

__device__ __forceinline__ float fast_gelu(float v) {
    const float c0 = 0.7978845608028654f;     // sqrt(2/pi)
    const float c1 = 0.044715f;
    float u = c0 * (v + c1 * v * v * v);
    // tanh(u) = 1 - 2/(exp(2u)+1); exp overflow -> t=1, underflow -> t=-1 (both correct)
    float e = __expf(2.0f * u);
    float t = 1.0f - __fdividef(2.0f, e + 1.0f);
    return 0.5f * v * (1.0f + t);
}

// Pack W1 (70x128, K zero-padded to 96) and W2 (128x64) into MFMA B-fragment
// order: region (s-step, j-tile) of 64 lanes x 8 bf16; lane: col = j*16+(l&15),
// k = s*32 + (l>>4)*8 + e. Same k mapping is used for A fragments, so the
// result is layout-exact regardless of hardware's canonical intra-lane order.
__global__ __launch_bounds__(256) void pack_weights_kernel(
    const float* __restrict__ W1, const float* __restrict__ W2,
    int4* __restrict__ W1p, int4* __restrict__ W2p)
{
    const int idx = blockIdx.x * 256 + threadIdx.x;
    unsigned short vals[8];
    if (idx < 1536) {                      // 24 regions (3 s x 8 j) x 64 lanes
        const int r = idx >> 6, lane = idx & 63;
        const int s = r >> 3, j = r & 7;
        const int col = j * 16 + (lane & 15), g = lane >> 4;
        #pragma unroll
        for (int e = 0; e < 8; ++e) {
            const int k = s * 32 + g * 8 + e;
            const float f = (k < 70) ? W1[k * 128 + col] : 0.0f;
            vals[e] = f2bf(f);
        }
        int4 v;
        v.x = vals[0] | (vals[1] << 16); v.y = vals[2] | (vals[3] << 16);
        v.z = vals[4] | (vals[5] << 16); v.w = vals[6] | (vals[7] << 16);
        W1p[idx] = v;
    } else if (idx < 2560) {               // 16 regions (4 s x 4 j) x 64 lanes
        const int i2 = idx - 1536;
        const int r = i2 >> 6, lane = i2 & 63;
        const int s = r >> 2, j = r & 3;
        const int col = j * 16 + (lane & 15), g = lane >> 4;
        #pragma unroll
        for (int e = 0; e < 8; ++e) {
            const int k = s * 32 + g * 8 + e;
            vals[e] = f2bf(W2[k * 64 + col]);
        }
        int4 v;
        v.x = vals[0] | (vals[1] << 16); v.y = vals[2] | (vals[3] << 16);
        v.z = vals[4] | (vals[5] << 16); v.w = vals[6] | (vals[7] << 16);
        W2p[i2] = v;
    }
}

__global__ __launch_bounds__(256) void it_mfma_kernel(
    const float* __restrict__ y,     // [n_in][3]
    const float* __restrict__ xq,    // [n_out][3]
    const float* __restrict__ f_y,   // [n_in][64]
    const float* __restrict__ b1,    // [128]
    const float* __restrict__ b2,    // [64]
    const float* __restrict__ av,    // [128]
    const int*   __restrict__ nbr,   // [n_out*32]
    const int4*  __restrict__ W1p,   // packed B1 fragments
    const int4*  __restrict__ W2p,   // packed B2 fragments
    float*       __restrict__ out,   // [n_out][64]
    int n_out)
{
    // A fragments live in LDS in per-lane order: region*1KB + lane*16B.
    __shared__ int4 sA1[6 * 64];             // edge_in: (tm 0..1, s 0..2)
    __shared__ int4 sA2[8 * 64];             // h:       (tm 0..1, s 0..3)
    __shared__ float s_part[4][KNBR];        // per-wave score partials

    const int tid = threadIdx.x;
    const int q   = blockIdx.x;
    const int w   = tid >> 6;                // wave 0..3
    const int l   = tid & 63;                // lane

    // ---------------- phase 1: gather -> bf16 A1 fragments ----------------
    {
        const int e = tid >> 3, kb = tid & 7;          // edge, k-block(8)
        const int ni = nbr[q * KNBR + e];
        const float* f = f_y + (long)ni * 64;
        float v[8];
        if (kb == 0) {                                  // k0..7: y,x,f0,f1
            v[0] = y[ni * 3 + 0]; v[1] = y[ni * 3 + 1]; v[2] = y[ni * 3 + 2];
            v[3] = xq[q * 3 + 0]; v[4] = xq[q * 3 + 1]; v[5] = xq[q * 3 + 2];
            float2 t = *(const float2*)(f);
            v[6] = t.x; v[7] = t.y;
        } else {                                        // k=8kb..8kb+7 -> f[8kb-6..8kb+1]
            const int k0 = kb * 8 - 6;
            float2 t0 = *(const float2*)(f + k0);
            float2 t1 = *(const float2*)(f + k0 + 2);
            float2 t2 = *(const float2*)(f + k0 + 4);
            float2 t3 = *(const float2*)(f + k0 + 6);
            v[0] = t0.x; v[1] = t0.y; v[2] = t1.x; v[3] = t1.y;
            v[4] = t2.x; v[5] = t2.y; v[6] = t3.x; v[7] = t3.y;
        }
        int4 pk;
        pk.x = f2bf(v[0]) | (f2bf(v[1]) << 16);
        pk.y = f2bf(v[2]) | (f2bf(v[3]) << 16);
        pk.z = f2bf(v[4]) | (f2bf(v[5]) << 16);
        pk.w = f2bf(v[6]) | (f2bf(v[7]) << 16);
        sA1[((e >> 4) * 3 + (kb >> 2)) * 64 + (e & 15) + 16 * (kb & 3)] = pk;
    }
    if (tid < 128) {                                    // k-blocks 8..11 (tail+pad)
        const int e = tid >> 2, kb = 8 + (tid & 3);
        float v[8] = {0.f, 0.f, 0.f, 0.f, 0.f, 0.f, 0.f, 0.f};
        if (kb == 8) {                                  // k64..69 -> f[58..63]
            const int ni = nbr[q * KNBR + e];
            const float* f = f_y + (long)ni * 64;
            float2 t0 = *(const float2*)(f + 58);
            float2 t1 = *(const float2*)(f + 60);
            float2 t2 = *(const float2*)(f + 62);
            v[0] = t0.x; v[1] = t0.y; v[2] = t1.x; v[3] = t1.y;
            v[4] = t2.x; v[5] = t2.y;
        }
        int4 pk;
        pk.x = f2bf(v[0]) | (f2bf(v[1]) << 16);
        pk.y = f2bf(v[2]) | (f2bf(v[3]) << 16);
        pk.z = f2bf(v[4]) | (f2bf(v[5]) << 16);
        pk.w = f2bf(v[6]) | (f2bf(v[7]) << 16);
        sA1[((e >> 4) * 3 + 2) * 64 + (e & 15) + 16 * (kb & 3)] = pk;
    }
    __syncthreads();

    // ---------------- phase 2: GEMM1 (M=32,N=128,K=96), wave w owns 32 cols --
    union Frag { int4 i; bf16x8 b; };
    const f32x4 zero4 = {0.f, 0.f, 0.f, 0.f};
    f32x4 acc[2][2] = {{zero4, zero4}, {zero4, zero4}};   // [tm][tn]
    #pragma unroll
    for (int s = 0; s < 3; ++s) {
        Frag a0, a1, bb0, bb1;
        a0.i  = sA1[(0 * 3 + s) * 64 + l];
        a1.i  = sA1[(1 * 3 + s) * 64 + l];
        bb0.i = W1p[(s * 8 + 2 * w + 0) * 64 + l];
        bb1.i = W1p[(s * 8 + 2 * w + 1) * 64 + l];
        acc[0][0] = __builtin_amdgcn_mfma_f32_16x16x32_bf16(a0.b, bb0.b, acc[0][0], 0, 0, 0);
        acc[0][1] = __builtin_amdgcn_mfma_f32_16x16x32_bf16(a0.b, bb1.b, acc[0][1], 0, 0, 0);
        acc[1][0] = __builtin_amdgcn_mfma_f32_16x16x32_bf16(a1.b, bb0.b, acc[1][0], 0, 0, 0);
        acc[1][1] = __builtin_amdgcn_mfma_f32_16x16x32_bf16(a1.b, bb1.b, acc[1][1], 0, 0, 0);
    }

    // ---------------- phase 3: bias+gelu (fp32), h->A2 frags, score partials --
    float sc[2][4] = {{0.f,0.f,0.f,0.f},{0.f,0.f,0.f,0.f}};
    unsigned short* sA2u = (unsigned short*)sA2;
    #pragma unroll
    for (int tm = 0; tm < 2; ++tm) {
        #pragma unroll
        for (int tn = 0; tn < 2; ++tn) {
            const int col = w * 32 + tn * 16 + (l & 15);   // global hidden col
            const float bb = b1[col];
            const float aa = av[col];
            const int kk = tn * 16 + (l & 15);             // k within wave's 32-slice
            const int lanep = 16 * (kk >> 3);
            #pragma unroll
            for (int r = 0; r < 4; ++r) {
                const float h = fast_gelu(acc[tm][tn][r] + bb);
                sc[tm][r] += h * aa;                        // fp32 score path
                const int em = (l >> 4) * 4 + r;            // edge & 15  (C/D row map)
                sA2u[(((tm * 4 + w) * 64) + em + lanep) * 8 + (kk & 7)] = f2bf(h);
            }
        }
    }
    #pragma unroll
    for (int m = 1; m < 16; m <<= 1) {
        #pragma unroll
        for (int tm = 0; tm < 2; ++tm)
            #pragma unroll
            for (int r = 0; r < 4; ++r)
                sc[tm][r] += __shfl_xor(sc[tm][r], m, 64);
    }
    if ((l & 15) == 0) {
        #pragma unroll
        for (int tm = 0; tm < 2; ++tm)
            #pragma unroll
            for (int r = 0; r < 4; ++r)
                s_part[w][tm * 16 + (l >> 4) * 4 + r] = sc[tm][r];
    }
    __syncthreads();

    // ---------------- phase 4: softmax (computed redundantly per wave) -------
    const int e32 = l & 31;
    float sv = s_part[0][e32] + s_part[1][e32] + s_part[2][e32] + s_part[3][e32];
    float mx = sv;
    #pragma unroll
    for (int m = 1; m < 32; m <<= 1) mx = fmaxf(mx, __shfl_xor(mx, m, 64));
    const float ex = __expf(sv - mx);
    float sm = ex;
    #pragma unroll
    for (int m = 1; m < 32; m <<= 1) sm += __shfl_xor(sm, m, 64);
    const float alpha = __fdividef(ex, sm);      // lane holds alpha[l&31]

    // ---------------- phase 5: GEMM2 (M=32,N=64,K=128), wave w owns 16 cols --
    f32x4 acc2[2] = {zero4, zero4};              // [tm]
    #pragma unroll
    for (int s = 0; s < 4; ++s) {
        Frag a0, a1, bb;
        a0.i = sA2[(0 * 4 + s) * 64 + l];
        a1.i = sA2[(1 * 4 + s) * 64 + l];
        bb.i = W2p[(s * 4 + w) * 64 + l];
        acc2[0] = __builtin_amdgcn_mfma_f32_16x16x32_bf16(a0.b, bb.b, acc2[0], 0, 0, 0);
        acc2[1] = __builtin_amdgcn_mfma_f32_16x16x32_bf16(a1.b, bb.b, acc2[1], 0, 0, 0);
    }

    // ---------------- phase 6: alpha-weighted reduce over 32 edges -----------
    float o = 0.f;
    #pragma unroll
    for (int tm = 0; tm < 2; ++tm) {
        #pragma unroll
        for (int r = 0; r < 4; ++r) {
            const int edge = tm * 16 + (l >> 4) * 4 + r;
            o += __shfl(alpha, edge, 64) * acc2[tm][r];
        }
    }
    o += __shfl_xor(o, 16, 64);
    o += __shfl_xor(o, 32, 64);
    if (l < 16) {
        const int col = w * 16 + l;
        out[q * 64 + col] = o + b2[col];
    }
}

extern "C" void kernel_launch(void* const* d_in, const int* in_sizes, int n_in,
                              void* d_out, int out_size, void* d_ws, size_t ws_size,
                              hipStream_t stream) {
    const float* y   = (const float*)d_in[0];
    const float* xq  = (const float*)d_in[1];
    const float* f_y = (const float*)d_in[2];
    const float* W1  = (const float*)d_in[3];
    const float* b1  = (const float*)d_in[4];
    const float* W2  = (const float*)d_in[5];
    const float* b2  = (const float*)d_in[6];
    const float* av  = (const float*)d_in[7];
    const int*   nbr = (const int*)d_in[8];
    float* out = (float*)d_out;

    const int n_out = in_sizes[1] / 3;      // x is [n_out][3]

    int4* W1p = (int4*)d_ws;                // 1536 frags = 24 KB
    int4* W2p = W1p + 1536;                 // 1024 frags = 16 KB

    pack_weights_kernel<<<10, 256, 0, stream>>>(W1, W2, W1p, W2p);
    it_mfma_kernel<<<n_out, 256, 0, stream>>>(y, xq, f_y, b1, b2, av, nbr,
                                              W1p, W2p, out, n_out);
}

// Round 3
// 142.894 us; speedup vs baseline: 4.1965x; 1.0198x over previous
//
#include <hip/hip_runtime.h>

typedef __attribute__((ext_vector_type(8))) short bf16x8;
typedef __attribute__((ext_vector_type(4))) float f32x4;

#define KNBR 32

union Frag { int4 i; bf16x8 b; };

__device__ __forceinline__ unsigned short f2bf(float f) {
    unsigned u = __float_as_uint(f);
    u += 0x7FFFu + ((u >> 16) & 1u);          // RNE to bf16
    return (unsigned short)(u >> 16);
}

// one instruction packs two fp32 -> two bf16 (dst.lo = src0, dst.hi = src1)
__device__ __forceinline__ unsigned cvt_pk_bf16(float lo, float hi) {
    unsigned r;
    asm("v_cvt_pk_bf16_f32 %0, %1, %2" : "=v"(r) : "v"(lo), "v"(hi));
    return r;
}

// gelu_tanh(v) = v * sigmoid(2*c0*(v + c1 v^3))  (exactly the tanh form)
__device__ __forceinline__ float fast_gelu(float v) {
    const float c1 = 0.044715f;
    const float n2c0 = -1.5957691216057308f;  // -2*sqrt(2/pi)
    float p = v * fmaf(c1, v * v, 1.0f);
    float e = __expf(n2c0 * p);               // exp(-2u)
    return v * __fdividef(1.0f, 1.0f + e);
}

// W1 packed as A-fragments of W1^T (row = hidden, k = input dim, zero-pad 70->96):
//   region (mt 0..7, s 0..2), lane l, elem e: row = mt*16+(l&15), k = s*32+(l>>4)*8+e
// W2 packed as B-fragments with the GEMM2 k-map matching h-in-register layout:
//   region (s 0..3, nt 0..3), lane l, elem e: col = nt*16+(l&15),
//   k = s*32 + (l>>4)*4 + (e&3) + 16*(e>>2)
__global__ __launch_bounds__(256) void pack_weights_kernel(
    const float* __restrict__ W1, const float* __restrict__ W2,
    int4* __restrict__ W1p, int4* __restrict__ W2p)
{
    const int idx = blockIdx.x * 256 + threadIdx.x;
    unsigned short vals[8];
    if (idx < 1536) {                      // 24 regions x 64 lanes
        const int r = idx >> 6, lane = idx & 63;
        const int mt = r / 3, s = r - mt * 3;
        const int row = mt * 16 + (lane & 15), g = lane >> 4;
        #pragma unroll
        for (int e = 0; e < 8; ++e) {
            const int k = s * 32 + g * 8 + e;
            vals[e] = f2bf(k < 70 ? W1[k * 128 + row] : 0.0f);
        }
        int4 v;
        v.x = vals[0] | (vals[1] << 16); v.y = vals[2] | (vals[3] << 16);
        v.z = vals[4] | (vals[5] << 16); v.w = vals[6] | (vals[7] << 16);
        W1p[idx] = v;
    } else if (idx < 2560) {               // 16 regions x 64 lanes
        const int i2 = idx - 1536;
        const int r = i2 >> 6, lane = i2 & 63;
        const int s = r >> 2, nt = r & 3;
        const int col = nt * 16 + (lane & 15), g = lane >> 4;
        #pragma unroll
        for (int e = 0; e < 8; ++e) {
            const int k = s * 32 + g * 4 + (e & 3) + 16 * (e >> 2);
            vals[e] = f2bf(W2[k * 64 + col]);
        }
        int4 v;
        v.x = vals[0] | (vals[1] << 16); v.y = vals[2] | (vals[3] << 16);
        v.z = vals[4] | (vals[5] << 16); v.w = vals[6] | (vals[7] << 16);
        W2p[i2] = v;
    }
}

__global__ __launch_bounds__(256) void it_mfma_kernel(
    const float* __restrict__ y,     // [n_in][3]
    const float* __restrict__ xq,    // [n_out][3]
    const float* __restrict__ f_y,   // [n_in][64]
    const float* __restrict__ b1,    // [128]
    const float* __restrict__ b2,    // [64]
    const float* __restrict__ av,    // [128]
    const int*   __restrict__ nbr,   // [n_out*32]
    const int4*  __restrict__ W1p,   // packed W1^T A-fragments
    const int4*  __restrict__ W2p,   // packed W2 B-fragments (custom k-map)
    float*       __restrict__ out,   // [n_out][64]
    int n_out)
{
    __shared__ int4  sA1[6 * 64];          // edge_in^T B-frags: region nt*3+s
    __shared__ float s_part[4][KNBR];      // per-wave score partials
    __shared__ float s_out[4][64];         // per-wave GEMM2 K-partials

    const int tid = threadIdx.x;
    const int q   = blockIdx.x;
    const int w   = tid >> 6;              // wave 0..3
    const int l   = tid & 63;              // lane

    // ---------------- phase 1: gather -> bf16 B1 fragments (col = edge) -----
    {
        const int e = tid >> 3, kb = tid & 7;           // edge, k-block(8)
        const int ni = nbr[q * KNBR + e];
        const float* f = f_y + (long)ni * 64;
        float v[8];
        if (kb == 0) {                                   // k0..7: y,x,f0,f1
            v[0] = y[ni * 3 + 0]; v[1] = y[ni * 3 + 1]; v[2] = y[ni * 3 + 2];
            v[3] = xq[q * 3 + 0]; v[4] = xq[q * 3 + 1]; v[5] = xq[q * 3 + 2];
            float2 t = *(const float2*)(f);
            v[6] = t.x; v[7] = t.y;
        } else {                                         // k=8kb.. -> f[8kb-6..]
            const int k0 = kb * 8 - 6;
            float2 t0 = *(const float2*)(f + k0);
            float2 t1 = *(const float2*)(f + k0 + 2);
            float2 t2 = *(const float2*)(f + k0 + 4);
            float2 t3 = *(const float2*)(f + k0 + 6);
            v[0] = t0.x; v[1] = t0.y; v[2] = t1.x; v[3] = t1.y;
            v[4] = t2.x; v[5] = t2.y; v[6] = t3.x; v[7] = t3.y;
        }
        int4 pk;
        pk.x = cvt_pk_bf16(v[0], v[1]);
        pk.y = cvt_pk_bf16(v[2], v[3]);
        pk.z = cvt_pk_bf16(v[4], v[5]);
        pk.w = cvt_pk_bf16(v[6], v[7]);
        sA1[((e >> 4) * 3 + (kb >> 2)) * 64 + (e & 15) + 16 * (kb & 3)] = pk;
    }
    if (tid < 128) {                                     // k-blocks 8..11 (tail+pad)
        const int e = tid >> 2, kb = 8 + (tid & 3);
        int4 pk = {0, 0, 0, 0};
        if (kb == 8) {                                   // k64..69 -> f[58..63]
            const int ni = nbr[q * KNBR + e];
            const float* f = f_y + (long)ni * 64;
            float2 t0 = *(const float2*)(f + 58);
            float2 t1 = *(const float2*)(f + 60);
            float2 t2 = *(const float2*)(f + 62);
            pk.x = cvt_pk_bf16(t0.x, t0.y);
            pk.y = cvt_pk_bf16(t1.x, t1.y);
            pk.z = cvt_pk_bf16(t2.x, t2.y);
        }
        sA1[((e >> 4) * 3 + 2) * 64 + (e & 15) + 16 * (kb & 3)] = pk;
    }
    __syncthreads();

    // ---------- phase 2: GEMM1^T: h^T[hid][edge], wave w -> hid w*32..+31 ----
    const f32x4 zero4 = {0.f, 0.f, 0.f, 0.f};
    f32x4 acc[2][2] = {{zero4, zero4}, {zero4, zero4}};  // [mt(hid tile)][nt(edge tile)]
    #pragma unroll
    for (int s = 0; s < 3; ++s) {
        Frag a0, a1, e0, e1;
        a0.i = W1p[((2 * w + 0) * 3 + s) * 64 + l];
        a1.i = W1p[((2 * w + 1) * 3 + s) * 64 + l];
        e0.i = sA1[(0 * 3 + s) * 64 + l];
        e1.i = sA1[(1 * 3 + s) * 64 + l];
        acc[0][0] = __builtin_amdgcn_mfma_f32_16x16x32_bf16(a0.b, e0.b, acc[0][0], 0, 0, 0);
        acc[0][1] = __builtin_amdgcn_mfma_f32_16x16x32_bf16(a0.b, e1.b, acc[0][1], 0, 0, 0);
        acc[1][0] = __builtin_amdgcn_mfma_f32_16x16x32_bf16(a1.b, e0.b, acc[1][0], 0, 0, 0);
        acc[1][1] = __builtin_amdgcn_mfma_f32_16x16x32_bf16(a1.b, e1.b, acc[1][1], 0, 0, 0);
    }

    // ------ phase 3: bias + gelu (fp32, in-register) + score partials -------
    // lane holds: edge = nt*16+(l&15), hidden = w*32 + mt*16 + (l>>4)*4 + r
    const int hb = w * 32 + ((l >> 4) << 2);
    float b1a[2][4], ava[2][4];
    *(float4*)&b1a[0][0] = *(const float4*)(b1 + hb);
    *(float4*)&b1a[1][0] = *(const float4*)(b1 + hb + 16);
    *(float4*)&ava[0][0] = *(const float4*)(av + hb);
    *(float4*)&ava[1][0] = *(const float4*)(av + hb + 16);

    float h[2][2][4];                      // [mt][nt][r]
    float sc0 = 0.f, sc1 = 0.f;
    #pragma unroll
    for (int mt = 0; mt < 2; ++mt) {
        #pragma unroll
        for (int r = 0; r < 4; ++r) {
            float g0 = fast_gelu(acc[mt][0][r] + b1a[mt][r]);
            float g1 = fast_gelu(acc[mt][1][r] + b1a[mt][r]);
            h[mt][0][r] = g0; h[mt][1][r] = g1;
            sc0 = fmaf(g0, ava[mt][r], sc0);
            sc1 = fmaf(g1, ava[mt][r], sc1);
        }
    }
    sc0 += __shfl_xor(sc0, 16, 64); sc0 += __shfl_xor(sc0, 32, 64);
    sc1 += __shfl_xor(sc1, 16, 64); sc1 += __shfl_xor(sc1, 32, 64);
    if (l < 16) { s_part[w][l] = sc0; s_part[w][l + 16] = sc1; }
    __syncthreads();

    // ---------------- phase 4: softmax (redundant per wave) ------------------
    const int e32 = l & 31;
    float sv = s_part[0][e32] + s_part[1][e32] + s_part[2][e32] + s_part[3][e32];
    float mx = sv;
    #pragma unroll
    for (int m = 1; m < 32; m <<= 1) mx = fmaxf(mx, __shfl_xor(mx, m, 64));
    float ex = __expf(sv - mx);
    float sm = ex;
    #pragma unroll
    for (int m = 1; m < 32; m <<= 1) sm += __shfl_xor(sm, m, 64);
    const float alpha = __fdividef(ex, sm);          // lane: alpha[l&31]

    // ------- phase 5: fold alpha into h, pack A2 in-register, GEMM2 ---------
    const float al0 = __shfl(alpha, l & 15, 64);          // alpha[edge l&15]
    const float al1 = __shfl(alpha, (l & 15) + 16, 64);   // alpha[edge l&15+16]
    Frag a2[2];                           // A2 tile nt: rows = edges nt*16..+15
    a2[0].i.x = cvt_pk_bf16(h[0][0][0] * al0, h[0][0][1] * al0);
    a2[0].i.y = cvt_pk_bf16(h[0][0][2] * al0, h[0][0][3] * al0);
    a2[0].i.z = cvt_pk_bf16(h[1][0][0] * al0, h[1][0][1] * al0);
    a2[0].i.w = cvt_pk_bf16(h[1][0][2] * al0, h[1][0][3] * al0);
    a2[1].i.x = cvt_pk_bf16(h[0][1][0] * al1, h[0][1][1] * al1);
    a2[1].i.y = cvt_pk_bf16(h[0][1][2] * al1, h[0][1][3] * al1);
    a2[1].i.z = cvt_pk_bf16(h[1][1][0] * al1, h[1][1][1] * al1);
    a2[1].i.w = cvt_pk_bf16(h[1][1][2] * al1, h[1][1][3] * al1);

    f32x4 acc2[2][4];                     // [et(edge tile)][nto(out tile)]
    #pragma unroll
    for (int nto = 0; nto < 4; ++nto) {
        Frag b2f;
        b2f.i = W2p[(w * 4 + nto) * 64 + l];
        acc2[0][nto] = __builtin_amdgcn_mfma_f32_16x16x32_bf16(a2[0].b, b2f.b, zero4, 0, 0, 0);
        acc2[1][nto] = __builtin_amdgcn_mfma_f32_16x16x32_bf16(a2[1].b, b2f.b, zero4, 0, 0, 0);
    }

    // -------- phase 6: sum over edges (rows) + cross-wave K reduction -------
    #pragma unroll
    for (int nto = 0; nto < 4; ++nto) {
        float o = ((acc2[0][nto][0] + acc2[0][nto][1]) + (acc2[0][nto][2] + acc2[0][nto][3]))
                + ((acc2[1][nto][0] + acc2[1][nto][1]) + (acc2[1][nto][2] + acc2[1][nto][3]));
        o += __shfl_xor(o, 16, 64);
        o += __shfl_xor(o, 32, 64);
        if (l < 16) s_out[w][l + 16 * nto] = o;
    }
    __syncthreads();
    if (tid < 64) {
        out[q * 64 + tid] = s_out[0][tid] + s_out[1][tid] + s_out[2][tid]
                          + s_out[3][tid] + b2[tid];
    }
}

extern "C" void kernel_launch(void* const* d_in, const int* in_sizes, int n_in,
                              void* d_out, int out_size, void* d_ws, size_t ws_size,
                              hipStream_t stream) {
    const float* y   = (const float*)d_in[0];
    const float* xq  = (const float*)d_in[1];
    const float* f_y = (const float*)d_in[2];
    const float* W1  = (const float*)d_in[3];
    const float* b1  = (const float*)d_in[4];
    const float* W2  = (const float*)d_in[5];
    const float* b2  = (const float*)d_in[6];
    const float* av  = (const float*)d_in[7];
    const int*   nbr = (const int*)d_in[8];
    float* out = (float*)d_out;

    const int n_out = in_sizes[1] / 3;      // x is [n_out][3]

    int4* W1p = (int4*)d_ws;                // 1536 frags = 24 KB
    int4* W2p = W1p + 1536;                 // 1024 frags = 16 KB

    pack_weights_kernel<<<10, 256, 0, stream>>>(W1, W2, W1p, W2p);
    it_mfma_kernel<<<n_out, 256, 0, stream>>>(y, xq, f_y, b1, b2, av, nbr,
                                              W1p, W2p, out, n_out);
}

// Round 4
// 131.180 us; speedup vs baseline: 4.5713x; 1.0893x over previous
//
#include <hip/hip_runtime.h>

typedef __attribute__((ext_vector_type(8))) short bf16x8;
typedef __attribute__((ext_vector_type(4))) float f32x4;

#define KNBR 32

union Frag { int4 i; bf16x8 b; };

__device__ __forceinline__ unsigned short f2bf(float f) {
    unsigned u = __float_as_uint(f);
    u += 0x7FFFu + ((u >> 16) & 1u);          // RNE to bf16
    return (unsigned short)(u >> 16);
}

// one instruction packs two fp32 -> two bf16 (dst.lo = src0, dst.hi = src1)
__device__ __forceinline__ unsigned cvt_pk_bf16(float lo, float hi) {
    unsigned r;
    asm("v_cvt_pk_bf16_f32 %0, %1, %2" : "=v"(r) : "v"(lo), "v"(hi));
    return r;
}

// gelu_tanh(v) = v * sigmoid(2*c0*(v + c1 v^3))  (exactly the tanh form)
__device__ __forceinline__ float fast_gelu(float v) {
    const float c1 = 0.044715f;
    const float n2c0 = -1.5957691216057308f;  // -2*sqrt(2/pi)
    float p = v * fmaf(c1, v * v, 1.0f);
    float e = __expf(n2c0 * p);               // exp(-2u)
    return v * __fdividef(1.0f, 1.0f + e);
}

// k-SLOT REMAP (slot = MFMA contraction index, logical = reference k):
//   slot 0..63  -> edge_in logical k = slot+6   (f_y[0..63], 16B-aligned gathers)
//   slot 64..69 -> edge_in logical k = slot-64  (y0 y1 y2 x0 x1 x2)
//   slot 70..95 -> zero pad
// W1 packed as A-fragments of W1^T with the same slot map:
//   region (mt 0..7, s 0..2), lane l, elem e: row = mt*16+(l&15), slot = s*32+(l>>4)*8+e
// W2 packed as B-fragments with the GEMM2 k-map matching h-in-register layout:
//   region (s 0..3, nt 0..3), lane l, elem e: col = nt*16+(l&15),
//   k = s*32 + (l>>4)*4 + (e&3) + 16*(e>>2)
__global__ __launch_bounds__(256) void pack_weights_kernel(
    const float* __restrict__ W1, const float* __restrict__ W2,
    int4* __restrict__ W1p, int4* __restrict__ W2p)
{
    const int idx = blockIdx.x * 256 + threadIdx.x;
    unsigned short vals[8];
    if (idx < 1536) {                      // 24 regions x 64 lanes
        const int r = idx >> 6, lane = idx & 63;
        const int mt = r / 3, s = r - mt * 3;
        const int row = mt * 16 + (lane & 15), g = lane >> 4;
        #pragma unroll
        for (int e = 0; e < 8; ++e) {
            const int k = s * 32 + g * 8 + e;          // slot index
            float f;
            if      (k < 64) f = W1[(k + 6) * 128 + row];   // f_y features
            else if (k < 70) f = W1[(k - 64) * 128 + row];  // y,x coords
            else             f = 0.0f;
            vals[e] = f2bf(f);
        }
        int4 v;
        v.x = vals[0] | (vals[1] << 16); v.y = vals[2] | (vals[3] << 16);
        v.z = vals[4] | (vals[5] << 16); v.w = vals[6] | (vals[7] << 16);
        W1p[idx] = v;
    } else if (idx < 2560) {               // 16 regions x 64 lanes
        const int i2 = idx - 1536;
        const int r = i2 >> 6, lane = i2 & 63;
        const int s = r >> 2, nt = r & 3;
        const int col = nt * 16 + (lane & 15), g = lane >> 4;
        #pragma unroll
        for (int e = 0; e < 8; ++e) {
            const int k = s * 32 + g * 4 + (e & 3) + 16 * (e >> 2);
            vals[e] = f2bf(W2[k * 64 + col]);
        }
        int4 v;
        v.x = vals[0] | (vals[1] << 16); v.y = vals[2] | (vals[3] << 16);
        v.z = vals[4] | (vals[5] << 16); v.w = vals[6] | (vals[7] << 16);
        W2p[i2] = v;
    }
}

__global__ __launch_bounds__(256) void it_mfma_kernel(
    const float* __restrict__ y,     // [n_in][3]
    const float* __restrict__ xq,    // [n_out][3]
    const float* __restrict__ f_y,   // [n_in][64]
    const float* __restrict__ b1,    // [128]
    const float* __restrict__ b2,    // [64]
    const float* __restrict__ av,    // [128]
    const int*   __restrict__ nbr,   // [n_out*32]
    const int4*  __restrict__ W1p,   // packed W1^T A-fragments (slot map)
    const int4*  __restrict__ W2p,   // packed W2 B-fragments (custom k-map)
    float*       __restrict__ out,   // [n_out][64]
    int n_out)
{
    __shared__ int4  sA1[6 * 64];          // edge_in^T B-frags: region nt*3+s
    __shared__ float s_part[4][KNBR];      // per-wave score partials
    __shared__ float s_out[4][64];         // per-wave GEMM2 K-partials

    const int tid = threadIdx.x;
    const int q   = blockIdx.x;
    const int w   = tid >> 6;              // wave 0..3
    const int l   = tid & 63;              // lane

    // ---- prefetch W1 A-fragments into registers (latency hides under gather)
    Frag wa[2][3];
    #pragma unroll
    for (int mt = 0; mt < 2; ++mt)
        #pragma unroll
        for (int s = 0; s < 3; ++s)
            wa[mt][s].i = W1p[((2 * w + mt) * 3 + s) * 64 + l];

    // ---------------- phase 1: gather -> bf16 B1 fragments (col = edge) -----
    // slots 0..63 = f_y row (two aligned dwordx4 per thread)
    {
        const int e = tid & 31;            // edge  (coalesced nbr read)
        const int c = tid >> 5;            // chunk 0..7 (slots 8c..8c+7)
        const int ni = nbr[q * KNBR + e];
        const float4* f4 = (const float4*)(f_y + (long)ni * 64);
        float4 t0 = f4[c * 2 + 0];
        float4 t1 = f4[c * 2 + 1];
        int4 pk;
        pk.x = cvt_pk_bf16(t0.x, t0.y);
        pk.y = cvt_pk_bf16(t0.z, t0.w);
        pk.z = cvt_pk_bf16(t1.x, t1.y);
        pk.w = cvt_pk_bf16(t1.z, t1.w);
        sA1[((e >> 4) * 3 + (c >> 2)) * 64 + (e & 15) + 16 * (c & 3)] = pk;
    }
    // slots 64..95: coords (64..69) + zero pad, region s=2
    if (tid < 128) {
        const int e2 = tid >> 2, g = tid & 3;
        int4 pk2 = {0, 0, 0, 0};
        if (g == 0) {
            const int ni2 = nbr[q * KNBR + e2];
            float2 y01 = *(const float2*)(y + ni2 * 3);
            float  yz  = y[ni2 * 3 + 2];
            float2 x01 = *(const float2*)(xq + q * 3);
            float  xz  = xq[q * 3 + 2];
            pk2.x = cvt_pk_bf16(y01.x, y01.y);
            pk2.y = cvt_pk_bf16(yz,    x01.x);
            pk2.z = cvt_pk_bf16(x01.y, xz);
        }
        sA1[((e2 >> 4) * 3 + 2) * 64 + (e2 & 15) + 16 * g] = pk2;
    }
    __syncthreads();

    // ---------- phase 2: GEMM1^T: h^T[hid][edge], wave w -> hid w*32..+31 ----
    const f32x4 zero4 = {0.f, 0.f, 0.f, 0.f};
    f32x4 acc[2][2] = {{zero4, zero4}, {zero4, zero4}};  // [mt(hid tile)][nt(edge tile)]
    #pragma unroll
    for (int s = 0; s < 3; ++s) {
        Frag e0, e1;
        e0.i = sA1[(0 * 3 + s) * 64 + l];
        e1.i = sA1[(1 * 3 + s) * 64 + l];
        acc[0][0] = __builtin_amdgcn_mfma_f32_16x16x32_bf16(wa[0][s].b, e0.b, acc[0][0], 0, 0, 0);
        acc[0][1] = __builtin_amdgcn_mfma_f32_16x16x32_bf16(wa[0][s].b, e1.b, acc[0][1], 0, 0, 0);
        acc[1][0] = __builtin_amdgcn_mfma_f32_16x16x32_bf16(wa[1][s].b, e0.b, acc[1][0], 0, 0, 0);
        acc[1][1] = __builtin_amdgcn_mfma_f32_16x16x32_bf16(wa[1][s].b, e1.b, acc[1][1], 0, 0, 0);
    }

    // ---- issue W2 fragment loads now; consumed in phase 5 (hides under gelu)
    Frag b2f[4];
    #pragma unroll
    for (int nto = 0; nto < 4; ++nto)
        b2f[nto].i = W2p[(w * 4 + nto) * 64 + l];

    // ------ phase 3: bias + gelu (fp32, in-register) + score partials -------
    // lane holds: edge = nt*16+(l&15), hidden = w*32 + mt*16 + (l>>4)*4 + r
    const int hb = w * 32 + ((l >> 4) << 2);
    float b1a[2][4], ava[2][4];
    *(float4*)&b1a[0][0] = *(const float4*)(b1 + hb);
    *(float4*)&b1a[1][0] = *(const float4*)(b1 + hb + 16);
    *(float4*)&ava[0][0] = *(const float4*)(av + hb);
    *(float4*)&ava[1][0] = *(const float4*)(av + hb + 16);

    float h[2][2][4];                      // [mt][nt][r]
    float sc0 = 0.f, sc1 = 0.f;
    #pragma unroll
    for (int mt = 0; mt < 2; ++mt) {
        #pragma unroll
        for (int r = 0; r < 4; ++r) {
            float g0 = fast_gelu(acc[mt][0][r] + b1a[mt][r]);
            float g1 = fast_gelu(acc[mt][1][r] + b1a[mt][r]);
            h[mt][0][r] = g0; h[mt][1][r] = g1;
            sc0 = fmaf(g0, ava[mt][r], sc0);
            sc1 = fmaf(g1, ava[mt][r], sc1);
        }
    }
    sc0 += __shfl_xor(sc0, 16, 64); sc0 += __shfl_xor(sc0, 32, 64);
    sc1 += __shfl_xor(sc1, 16, 64); sc1 += __shfl_xor(sc1, 32, 64);
    if (l < 16) { s_part[w][l] = sc0; s_part[w][l + 16] = sc1; }
    __syncthreads();

    // ---------------- phase 4: softmax (redundant per wave) ------------------
    const int e32 = l & 31;
    float sv = s_part[0][e32] + s_part[1][e32] + s_part[2][e32] + s_part[3][e32];
    float mx = sv;
    #pragma unroll
    for (int m = 1; m < 32; m <<= 1) mx = fmaxf(mx, __shfl_xor(mx, m, 64));
    float ex = __expf(sv - mx);
    float sm = ex;
    #pragma unroll
    for (int m = 1; m < 32; m <<= 1) sm += __shfl_xor(sm, m, 64);
    const float alpha = __fdividef(ex, sm);          // lane: alpha[l&31]

    // ------- phase 5: fold alpha into h, pack A2 in-register, GEMM2 ---------
    const float al0 = __shfl(alpha, l & 15, 64);          // alpha[edge l&15]
    const float al1 = __shfl(alpha, (l & 15) + 16, 64);   // alpha[edge l&15+16]
    Frag a2[2];                           // A2 tile nt: rows = edges nt*16..+15
    a2[0].i.x = cvt_pk_bf16(h[0][0][0] * al0, h[0][0][1] * al0);
    a2[0].i.y = cvt_pk_bf16(h[0][0][2] * al0, h[0][0][3] * al0);
    a2[0].i.z = cvt_pk_bf16(h[1][0][0] * al0, h[1][0][1] * al0);
    a2[0].i.w = cvt_pk_bf16(h[1][0][2] * al0, h[1][0][3] * al0);
    a2[1].i.x = cvt_pk_bf16(h[0][1][0] * al1, h[0][1][1] * al1);
    a2[1].i.y = cvt_pk_bf16(h[0][1][2] * al1, h[0][1][3] * al1);
    a2[1].i.z = cvt_pk_bf16(h[1][1][0] * al1, h[1][1][1] * al1);
    a2[1].i.w = cvt_pk_bf16(h[1][1][2] * al1, h[1][1][3] * al1);

    f32x4 acc2[2][4];                     // [et(edge tile)][nto(out tile)]
    #pragma unroll
    for (int nto = 0; nto < 4; ++nto) {
        acc2[0][nto] = __builtin_amdgcn_mfma_f32_16x16x32_bf16(a2[0].b, b2f[nto].b, zero4, 0, 0, 0);
        acc2[1][nto] = __builtin_amdgcn_mfma_f32_16x16x32_bf16(a2[1].b, b2f[nto].b, zero4, 0, 0, 0);
    }

    // -------- phase 6: sum over edges (rows) + cross-wave K reduction -------
    #pragma unroll
    for (int nto = 0; nto < 4; ++nto) {
        float o = ((acc2[0][nto][0] + acc2[0][nto][1]) + (acc2[0][nto][2] + acc2[0][nto][3]))
                + ((acc2[1][nto][0] + acc2[1][nto][1]) + (acc2[1][nto][2] + acc2[1][nto][3]));
        o += __shfl_xor(o, 16, 64);
        o += __shfl_xor(o, 32, 64);
        if (l < 16) s_out[w][l + 16 * nto] = o;
    }
    __syncthreads();
    if (tid < 64) {
        out[q * 64 + tid] = s_out[0][tid] + s_out[1][tid] + s_out[2][tid]
                          + s_out[3][tid] + b2[tid];
    }
}

extern "C" void kernel_launch(void* const* d_in, const int* in_sizes, int n_in,
                              void* d_out, int out_size, void* d_ws, size_t ws_size,
                              hipStream_t stream) {
    const float* y   = (const float*)d_in[0];
    const float* xq  = (const float*)d_in[1];
    const float* f_y = (const float*)d_in[2];
    const float* W1  = (const float*)d_in[3];
    const float* b1  = (const float*)d_in[4];
    const float* W2  = (const float*)d_in[5];
    const float* b2  = (const float*)d_in[6];
    const float* av  = (const float*)d_in[7];
    const int*   nbr = (const int*)d_in[8];
    float* out = (float*)d_out;

    const int n_out = in_sizes[1] / 3;      // x is [n_out][3]

    int4* W1p = (int4*)d_ws;                // 1536 frags = 24 KB
    int4* W2p = W1p + 1536;                 // 1024 frags = 16 KB

    pack_weights_kernel<<<10, 256, 0, stream>>>(W1, W2, W1p, W2p);
    it_mfma_kernel<<<n_out, 256, 0, stream>>>(y, xq, f_y, b1, b2, av, nbr,
                                              W1p, W2p, out, n_out);
}